// Round 2
// baseline (471.783 us; speedup 1.0000x reference)
//
#include <hip/hip_runtime.h>
#include <hip/hip_bf16.h>
#include <math.h>

#define BSZ 128
#define K1  15360
#define N1  4096
#define N2  2048
#define MM  256

typedef __attribute__((ext_vector_type(8))) short          s16x8;
typedef __attribute__((ext_vector_type(8))) unsigned short u16x8;
typedef __attribute__((ext_vector_type(4))) unsigned short u16x4;
typedef __attribute__((ext_vector_type(4))) float          f32x4;

__device__ __forceinline__ unsigned short f2bf(float f) {
  unsigned int u = __builtin_bit_cast(unsigned int, f);
  u += 0x7FFFu + ((u >> 16) & 1u);           // round-to-nearest-even
  return (unsigned short)(u >> 16);
}

// ---------------- Kernel A: build X (bf16), rows 128..255 = flip(mct, last dim=6)
__global__ void build_x(const float* __restrict__ ct, const float* __restrict__ mct,
                        unsigned short* __restrict__ Xb) {
  int idx = blockIdx.x * blockDim.x + threadIdx.x;   // 0..491519 (groups of 8)
  int r  = idx / (K1 / 8);
  int kg = idx - r * (K1 / 8);
  int k0 = kg * 8;
  unsigned short o[8];
  if (r < BSZ) {
    const float* src = ct + (long)r * K1 + k0;
    f32x4 v0 = *(const f32x4*)src;
    f32x4 v1 = *(const f32x4*)(src + 4);
    o[0]=f2bf(v0.x); o[1]=f2bf(v0.y); o[2]=f2bf(v0.z); o[3]=f2bf(v0.w);
    o[4]=f2bf(v1.x); o[5]=f2bf(v1.y); o[6]=f2bf(v1.z); o[7]=f2bf(v1.w);
  } else {
    const float* src = mct + (long)(r - BSZ) * K1;
#pragma unroll
    for (int j = 0; j < 8; ++j) {
      int k = k0 + j;
      int w = k % 6;                       // flip axis 3 (size 6)
      o[j] = f2bf(src[k + 5 - 2 * w]);
    }
  }
  u16x8 vv;
#pragma unroll
  for (int j = 0; j < 8; ++j) vv[j] = o[j];
  *(u16x8*)(Xb + (long)r * K1 + k0) = vv;
}

// ---------------- Kernel B: GEMM1 partials. C[m,n]=sum_k X[m,k]*W1[n,k]
// BM=256 (full M, W1 read exactly once), BN=128, Ksplit=8 (slice 1920), 512 thr.
__launch_bounds__(512, 1)
__global__ void gemm1(const unsigned short* __restrict__ Xb,
                      const float* __restrict__ W1,
                      float* __restrict__ part) {
  __shared__ __align__(16) unsigned short As[2][256][40];  // pad 32->40 (conflict-free)
  __shared__ __align__(16) unsigned short Bs[2][128][40];
  const int tid = threadIdx.x;
  const int nb  = blockIdx.x & 31;       // 32 n-blocks of 128
  const int ks  = blockIdx.x >> 5;       // 8 k-splits
  const int lane = tid & 63;
  const int w  = tid >> 6;               // 8 waves: 2 (m) x 4 (n)
  const int wm = w >> 2;                 // 0..1  -> 128 rows
  const int wn = w & 3;                  // 0..3  -> 32 cols
  const long kbase0 = (long)ks * 1920;

  const int a_row = tid >> 1, a_kh = (tid & 1) * 16;
  const int b_row = tid >> 2, b_kq = (tid & 3) * 8;
  const unsigned short* aSrc = Xb + (long)a_row * K1 + kbase0 + a_kh;
  const float*          bSrc = W1 + (long)(nb * 128 + b_row) * K1 + kbase0 + b_kq;

  f32x4 acc[8][2];
#pragma unroll
  for (int i = 0; i < 8; ++i) { acc[i][0] = (f32x4){0,0,0,0}; acc[i][1] = (f32x4){0,0,0,0}; }

  auto stage = [&](int buf, int it) {
    const int ko = it * 32;
    u16x8 v0 = *(const u16x8*)(aSrc + ko);
    u16x8 v1 = *(const u16x8*)(aSrc + ko + 8);
    *(u16x8*)&As[buf][a_row][a_kh]     = v0;
    *(u16x8*)&As[buf][a_row][a_kh + 8] = v1;
    f32x4 f0 = *(const f32x4*)(bSrc + ko);
    f32x4 f1 = *(const f32x4*)(bSrc + ko + 4);
    u16x8 bv;
    bv[0]=f2bf(f0.x); bv[1]=f2bf(f0.y); bv[2]=f2bf(f0.z); bv[3]=f2bf(f0.w);
    bv[4]=f2bf(f1.x); bv[5]=f2bf(f1.y); bv[6]=f2bf(f1.z); bv[7]=f2bf(f1.w);
    *(u16x8*)&Bs[buf][b_row][b_kq] = bv;
  };

  const int kq = (lane >> 4) * 8;  // A/B frag: lane holds [idx=lane&15][k=(lane>>4)*8+j]
  const int mr = lane & 15;
  int buf = 0;
  stage(0, 0);
  for (int it = 0; it < 60; ++it) {
    __syncthreads();
    if (it + 1 < 60) stage(buf ^ 1, it + 1);
    s16x8 bf0 = *(const s16x8*)&Bs[buf][wn * 32 + mr][kq];
    s16x8 bf1 = *(const s16x8*)&Bs[buf][wn * 32 + 16 + mr][kq];
#pragma unroll
    for (int mt = 0; mt < 8; ++mt) {
      s16x8 af = *(const s16x8*)&As[buf][wm * 128 + mt * 16 + mr][kq];
      acc[mt][0] = __builtin_amdgcn_mfma_f32_16x16x32_bf16(af, bf0, acc[mt][0], 0, 0, 0);
      acc[mt][1] = __builtin_amdgcn_mfma_f32_16x16x32_bf16(af, bf1, acc[mt][1], 0, 0, 0);
    }
    buf ^= 1;
  }
  // D layout: row m=(lane>>4)*4+r, col n=lane&15
  float* dst = part + (long)ks * MM * N1;
  const int mb = wm * 128 + (lane >> 4) * 4;
  const int nbase = nb * 128 + wn * 32 + (lane & 15);
#pragma unroll
  for (int mt = 0; mt < 8; ++mt)
#pragma unroll
    for (int nt = 0; nt < 2; ++nt)
#pragma unroll
      for (int r = 0; r < 4; ++r)
        dst[(long)(mb + mt * 16 + r) * N1 + (nbase + nt * 16)] = acc[mt][nt][r];
}

// ---------------- Kernel C: H1b = bf16(relu(sum_s part1 + b1))
__global__ void reduce1(const float* __restrict__ part, const float* __restrict__ b1,
                        unsigned short* __restrict__ H1b) {
  long idx = (long)(blockIdx.x * blockDim.x + threadIdx.x) * 4;   // 256*4096 total
  f32x4 s = {0,0,0,0};
#pragma unroll
  for (int ksp = 0; ksp < 8; ++ksp)
    s += *(const f32x4*)(part + (long)ksp * MM * N1 + idx);
  f32x4 bb = *(const f32x4*)(b1 + (int)(idx & (N1 - 1)));
  s += bb;
  u16x4 o;
  o[0] = f2bf(fmaxf(s.x, 0.f)); o[1] = f2bf(fmaxf(s.y, 0.f));
  o[2] = f2bf(fmaxf(s.z, 0.f)); o[3] = f2bf(fmaxf(s.w, 0.f));
  *(u16x4*)(H1b + idx) = o;
}

// ---------------- Kernel D: GEMM2 partials. BM=256, BN=64, Ksplit=8 (slice 512)
__launch_bounds__(512, 1)
__global__ void gemm2(const unsigned short* __restrict__ H1b,
                      const float* __restrict__ W2,
                      float* __restrict__ part) {
  __shared__ __align__(16) unsigned short As[2][256][40];
  __shared__ __align__(16) unsigned short Bs[2][64][40];
  const int tid = threadIdx.x;
  const int nb  = blockIdx.x & 31;       // 32 n-blocks of 64
  const int ks  = blockIdx.x >> 5;       // 8 k-splits
  const int lane = tid & 63;
  const int w  = tid >> 6;
  const int wm = w >> 1;                 // 0..3 -> 64 rows
  const int wn = w & 1;                  // 0..1 -> 32 cols
  const int kbase0 = ks * 512;

  const int a_row = tid >> 1, a_kh = (tid & 1) * 16;
  const int b_row = tid >> 3, b_kq = (tid & 7) * 4;
  const unsigned short* aSrc = H1b + (long)a_row * N1 + kbase0 + a_kh;
  const float*          bSrc = W2 + (long)(nb * 64 + b_row) * N1 + kbase0 + b_kq;

  f32x4 acc[4][2];
#pragma unroll
  for (int i = 0; i < 4; ++i) { acc[i][0] = (f32x4){0,0,0,0}; acc[i][1] = (f32x4){0,0,0,0}; }

  auto stage = [&](int buf, int it) {
    const int ko = it * 32;
    u16x8 v0 = *(const u16x8*)(aSrc + ko);
    u16x8 v1 = *(const u16x8*)(aSrc + ko + 8);
    *(u16x8*)&As[buf][a_row][a_kh]     = v0;
    *(u16x8*)&As[buf][a_row][a_kh + 8] = v1;
    f32x4 f0 = *(const f32x4*)(bSrc + ko);
    u16x4 bv;
    bv[0]=f2bf(f0.x); bv[1]=f2bf(f0.y); bv[2]=f2bf(f0.z); bv[3]=f2bf(f0.w);
    *(u16x4*)&Bs[buf][b_row][b_kq] = bv;
  };

  const int kq = (lane >> 4) * 8;
  const int mr = lane & 15;
  int buf = 0;
  stage(0, 0);
  for (int it = 0; it < 16; ++it) {
    __syncthreads();
    if (it + 1 < 16) stage(buf ^ 1, it + 1);
    s16x8 bf0 = *(const s16x8*)&Bs[buf][wn * 32 + mr][kq];
    s16x8 bf1 = *(const s16x8*)&Bs[buf][wn * 32 + 16 + mr][kq];
#pragma unroll
    for (int mt = 0; mt < 4; ++mt) {
      s16x8 af = *(const s16x8*)&As[buf][wm * 64 + mt * 16 + mr][kq];
      acc[mt][0] = __builtin_amdgcn_mfma_f32_16x16x32_bf16(af, bf0, acc[mt][0], 0, 0, 0);
      acc[mt][1] = __builtin_amdgcn_mfma_f32_16x16x32_bf16(af, bf1, acc[mt][1], 0, 0, 0);
    }
    buf ^= 1;
  }
  float* dst = part + (long)ks * MM * N2;
  const int mb = wm * 64 + (lane >> 4) * 4;
  const int nbase = nb * 64 + wn * 32 + (lane & 15);
#pragma unroll
  for (int mt = 0; mt < 4; ++mt)
#pragma unroll
    for (int nt = 0; nt < 2; ++nt)
#pragma unroll
      for (int r = 0; r < 4; ++r)
        dst[(long)(mb + mt * 16 + r) * N2 + (nbase + nt * 16)] = acc[mt][nt][r];
}

// ---------------- Kernel E: reduce + bias + relu + L2 normalize -> rn (f32)
__launch_bounds__(256, 1)
__global__ void reduce2norm(const float* __restrict__ part, const float* __restrict__ b2,
                            float* __restrict__ rn) {
  const int m = blockIdx.x;
  const int tid = threadIdx.x;
  __shared__ float red[4];
  f32x4 sv[2];
  float ss = 0.f;
#pragma unroll
  for (int g = 0; g < 2; ++g) {
    const int n = tid * 8 + g * 4;
    f32x4 s = {0,0,0,0};
#pragma unroll
    for (int ksp = 0; ksp < 8; ++ksp)
      s += *(const f32x4*)(part + ((long)ksp * MM + m) * N2 + n);
    s += *(const f32x4*)(b2 + n);
    s.x = fmaxf(s.x, 0.f); s.y = fmaxf(s.y, 0.f);
    s.z = fmaxf(s.z, 0.f); s.w = fmaxf(s.w, 0.f);
    sv[g] = s;
    ss += s.x*s.x + s.y*s.y + s.z*s.z + s.w*s.w;
  }
#pragma unroll
  for (int o = 32; o > 0; o >>= 1) ss += __shfl_down(ss, o);
  if ((tid & 63) == 0) red[tid >> 6] = ss;
  __syncthreads();
  const float tot = red[0] + red[1] + red[2] + red[3];
  const float inv = 1.f / fmaxf(sqrtf(tot), 1e-8f);
#pragma unroll
  for (int g = 0; g < 2; ++g) {
    const int n = tid * 8 + g * 4;
    f32x4 v = sv[g];
    v *= inv;
    *(f32x4*)(rn + (long)m * N2 + n) = v;
  }
}

// ---------------- Kernel F: sim partials (fp32). 16 i-tiles x 16 k-splits.
__launch_bounds__(256, 1)
__global__ void simk(const float* __restrict__ rn, float* __restrict__ psim) {
  const int itile = blockIdx.x & 15;
  const int ks    = blockIdx.x >> 4;      // 0..15, slice 128
  __shared__ float Ls[16][128];
  const int tid = threadIdx.x;
  {
    const int r = tid >> 4;
    const int c = (tid & 15) * 8;
    const float* src = rn + (long)(itile * 16 + r) * N2 + ks * 128 + c;
    *(f32x4*)&Ls[r][c]     = *(const f32x4*)src;
    *(f32x4*)&Ls[r][c + 4] = *(const f32x4*)(src + 4);
  }
  __syncthreads();
  float acc[16];
#pragma unroll
  for (int i = 0; i < 16; ++i) acc[i] = 0.f;
  const float* rnj = rn + (long)tid * N2 + ks * 128;
  for (int kk = 0; kk < 128; kk += 4) {
    f32x4 v = *(const f32x4*)(rnj + kk);
#pragma unroll
    for (int i = 0; i < 16; ++i) {
      f32x4 L = *(const f32x4*)&Ls[i][kk];   // broadcast across lanes
      acc[i] += v.x*L.x + v.y*L.y + v.z*L.z + v.w*L.w;
    }
  }
  float* dst = psim + ((long)ks * MM + itile * 16) * MM + tid;
#pragma unroll
  for (int i = 0; i < 16; ++i) dst[i * MM] = acc[i];
}

// ---------------- Kernel G: per-row loss
__global__ void rowloss(const float* __restrict__ psim, float* __restrict__ lossp) {
  const int i = blockIdx.x;
  const int lane = threadIdx.x;           // 64
  float den = 0.f, pos = 0.f;
#pragma unroll
  for (int t = 0; t < 4; ++t) {
    const int j = lane + t * 64;
    float s = 0.f;
#pragma unroll
    for (int ksp = 0; ksp < 16; ++ksp)
      s += psim[((long)ksp * MM + i) * MM + j];
    if (j == (i ^ 128)) pos = s;          // positives: diag offsets +-128
    if (j != i) den += expf(s * 2.f);     // 1/T = 2
  }
#pragma unroll
  for (int o = 32; o > 0; o >>= 1) { den += __shfl_down(den, o); pos += __shfl_down(pos, o); }
  if (lane == 0) lossp[i] = -(pos * 2.f - logf(den));
}

// ---------------- Kernel H: final mean
__global__ void finalk(const float* __restrict__ lossp, float* __restrict__ out) {
  const int tid = threadIdx.x;            // 256
  float v = lossp[tid];
#pragma unroll
  for (int o = 32; o > 0; o >>= 1) v += __shfl_down(v, o);
  __shared__ float red[4];
  if ((tid & 63) == 0) red[tid >> 6] = v;
  __syncthreads();
  if (tid == 0) out[0] = (red[0] + red[1] + red[2] + red[3]) * (1.f / 256.f);
}

extern "C" void kernel_launch(void* const* d_in, const int* in_sizes, int n_in,
                              void* d_out, int out_size, void* d_ws, size_t ws_size,
                              hipStream_t stream) {
  const float* ct  = (const float*)d_in[0];
  const float* mct = (const float*)d_in[1];
  const float* W1  = (const float*)d_in[2];
  const float* b1  = (const float*)d_in[3];
  const float* W2  = (const float*)d_in[4];
  const float* b2  = (const float*)d_in[5];
  float* out = (float*)d_out;
  char* ws = (char*)d_ws;

  // layout: Xb(7,864,320) | region(33,554,432: part1, then part2+rn+psim+lossp) | H1b(2,097,152)
  unsigned short* Xb   = (unsigned short*)ws;
  float* part1 = (float*)(ws + 7864320);
  unsigned short* H1b  = (unsigned short*)(ws + 7864320 + 33554432);
  float* part2 = (float*)(ws + 7864320);
  float* rn    = (float*)(ws + 7864320 + 16777216);
  float* psim  = (float*)(ws + 7864320 + 16777216 + 2097152);
  float* lossp = (float*)(ws + 7864320 + 16777216 + 2097152 + 4194304);

  build_x<<<1920, 256, 0, stream>>>(ct, mct, Xb);
  gemm1<<<256, 512, 0, stream>>>(Xb, W1, part1);
  reduce1<<<1024, 256, 0, stream>>>(part1, b1, H1b);
  gemm2<<<256, 512, 0, stream>>>(H1b, W2, part2);
  reduce2norm<<<MM, 256, 0, stream>>>(part2, b2, rn);
  simk<<<256, 256, 0, stream>>>(rn, psim);
  rowloss<<<MM, 64, 0, stream>>>(psim, lossp);
  finalk<<<1, 256, 0, stream>>>(lossp, out);
}